// Round 8
// baseline (677.986 us; speedup 1.0000x reference)
//
#include <hip/hip_runtime.h>
#include <hip/hip_cooperative_groups.h>
#include <math.h>

namespace cg = cooperative_groups;

// Problem constants
#define NB   16
#define HW   65536          // 256*256
#define NCHH 16             // hist pixel-chunks per (b,pair)

// Workspace layout (float offsets)
#define OFF_S    0          // [16][65536] channel-summed box/9 (dead after phase 2)
#define OFF_D    0          // [16][9][64][56] per-cell tap dots (overwrites dead S)
#define OFF_PH   1048576    // [1024][64] partial hists
#define OFF_PMN  1114112    // [128][64] partial mins (per 32x32 tile)
#define OFF_PMX  1122304    // [128][64] partial maxs
#define OFF_PT   1130496    // [1024] per-hist-block totals
// total floats: 1131520 (~4.53 MB)

__device__ __forceinline__ float leakyf(float v) { return v >= 0.f ? v : 0.01f * v; }

// ===================== shared phase bodies (used by mega + fallback) =========

__device__ __forceinline__ void phase_box(const float* __restrict__ x,
                                          float* __restrict__ ws,
                                          float lo, float hi,
                                          int b, int tile, int tid,
                                          float inp[36][37], float S[34][36],
                                          float smn[4][8], float smx[4][8])
{
    const int doy[8] = {-1, 1, -1, 1, -1, 1, 0, 0};
    const int dox[8] = {-1, 1,  0, 0,  1, -1, 1, -1};
    int h0 = (tile >> 3) * 32, w0 = (tile & 7) * 32;
    const float* xb = x + (size_t)b * 3 * HW;
    for (int i = tid; i < 36 * 36; i += 256) {
        int lh = i / 36, lw = i % 36;
        int gh = h0 - 2 + lh, gw = w0 - 2 + lw;
        float v = 0.f;
        if ((unsigned)gh < 256u && (unsigned)gw < 256u) {
            int p = gh * 256 + gw;
            v = xb[p] + xb[HW + p] + xb[2 * HW + p];
        }
        inp[lh][lw] = v;
    }
    __syncthreads();
    for (int i = tid; i < 34 * 34; i += 256) {
        int lh = i / 34, lw = i % 34;
        float s = 0.f;
        #pragma unroll
        for (int dy = 0; dy < 3; ++dy)
            #pragma unroll
            for (int dx = 0; dx < 3; ++dx)
                s += inp[lh + dy][lw + dx];
        S[lh][lw] = s / 9.0f;
    }
    __syncthreads();
    #pragma unroll
    for (int i = 0; i < 4; ++i) {
        int idx = i * 256 + tid;
        int r = idx >> 5, c = idx & 31;
        ws[OFF_S + b * HW + (h0 + r) * 256 + (w0 + c)] = S[r + 1][c + 1];
    }
    float vmn[8], vmx[8];
    #pragma unroll
    for (int o = 0; o < 8; ++o) { vmn[o] = 3.4e38f; vmx[o] = -3.4e38f; }
    #pragma unroll
    for (int i = 0; i < 4; ++i) {
        int idx = i * 256 + tid;
        int r = idx >> 5, c = idx & 31;
        int gh = h0 + r, gw = w0 + c;
        float sc = S[r + 1][c + 1];
        #pragma unroll
        for (int o = 0; o < 8; ++o) {
            int nh = gh + doy[o], nw = gw + dox[o];
            float off = ((unsigned)nh < 256u && (unsigned)nw < 256u)
                        ? S[r + 1 + doy[o]][c + 1 + dox[o]] : 0.f;
            float v = fminf(fmaxf(sc - off, lo), hi);
            vmn[o] = fminf(vmn[o], v);
            vmx[o] = fmaxf(vmx[o], v);
        }
    }
    #pragma unroll
    for (int o = 0; o < 8; ++o) {
        #pragma unroll
        for (int m = 1; m < 64; m <<= 1) {
            vmn[o] = fminf(vmn[o], __shfl_xor(vmn[o], m));
            vmx[o] = fmaxf(vmx[o], __shfl_xor(vmx[o], m));
        }
    }
    int wid = tid >> 6, lane = tid & 63;
    if (lane == 0) {
        #pragma unroll
        for (int o = 0; o < 8; ++o) { smn[wid][o] = vmn[o]; smx[wid][o] = vmx[o]; }
    }
    __syncthreads();
    if (tid < 8) {
        int o = tid;
        float mn = fminf(fminf(smn[0][o], smn[1][o]), fminf(smn[2][o], smn[3][o]));
        float mx = fmaxf(fmaxf(smx[0][o], smx[1][o]), fmaxf(smx[2][o], smx[3][o]));
        ws[OFF_PMN + (b * 8 + o) * 64 + tile] = mn;
        ws[OFF_PMX + (b * 8 + o) * 64 + tile] = mx;
    }
}

__device__ __forceinline__ void phase_hist(float* ws, float lo, float hi,
                                           int unit, int tid,
                                           float* lh /*4096*/, float sred[4])
{
    const int doy[8] = {-1, 1, -1, 1, -1, 1, 0, 0};
    const int dox[8] = {-1, 1,  0, 0,  1, -1, 1, -1};
    int bg = unit >> 4, ch = unit & 15;
    int b = bg >> 2, g = bg & 3;
    int dy0 = doy[2 * g], dx0 = dox[2 * g];
    int dy1 = doy[2 * g + 1], dx1 = dox[2 * g + 1];
    int warp = tid >> 6, lane = tid & 63;
    {
        int c0 = (b * 8 + 2 * g) * 64, c1 = (b * 8 + 2 * g + 1) * 64;
        float v;
        if      (warp == 0) v = ws[OFF_PMN + c0 + lane];
        else if (warp == 1) v = ws[OFF_PMX + c0 + lane];
        else if (warp == 2) v = ws[OFF_PMN + c1 + lane];
        else                v = ws[OFF_PMX + c1 + lane];
        bool isMin = (warp & 1) == 0;
        #pragma unroll
        for (int m = 1; m < 64; m <<= 1) {
            float o = __shfl_xor(v, m);
            v = isMin ? fminf(v, o) : fmaxf(v, o);
        }
        if (lane == 0) sred[warp] = v;
    }
    {
        float4 z4 = {0.f, 0.f, 0.f, 0.f};
        float4* l4 = (float4*)lh;
        l4[tid] = z4; l4[tid + 256] = z4; l4[tid + 512] = z4; l4[tid + 768] = z4;
    }
    __syncthreads();
    float mn0 = sred[0], mx0 = sred[1], mn1 = sred[2], mx1 = sred[3];
    float r0 = mx0 - mn0, r1 = mx1 - mn1;
    float lev0[8], lev1[8];
    #pragma unroll
    for (int q = 0; q < 8; ++q) {
        lev0[q] = __fadd_rn(mn0, __fmul_rn(r0, (float)q * 0.125f));
        lev1[q] = __fadd_rn(mn1, __fmul_rn(r1, (float)q * 0.125f));
    }
    const float* Sb = ws + OFF_S + b * HW;
    int col = tid & 63;
    int base = ch * (HW / NCHH);
    #pragma unroll
    for (int it = 0; it < (HW / NCHH) / 256; ++it) {
        int p = base + it * 256 + tid;
        int h = p >> 8, w = p & 255;
        float off0 = 0.f, off1 = 0.f;
        int nh = h + dy0, nw = w + dx0;
        if ((unsigned)nh < 256u && (unsigned)nw < 256u) off0 = Sb[nh * 256 + nw];
        nh = h + dy1; nw = w + dx1;
        if ((unsigned)nh < 256u && (unsigned)nw < 256u) off1 = Sb[nh * 256 + nw];
        float sc = Sb[p];
        float v0 = fminf(fmaxf(sc - off0, lo), hi);
        float v1 = fminf(fmaxf(sc - off1, lo), hi);
        int i0 = 0, j0 = 0;
        bool ilo = false, jlo = false;
        #pragma unroll
        for (int k = 1; k < 8; ++k) {
            i0 += (v0 >= lev0[k]); ilo |= (v0 == lev0[k]);
            j0 += (v1 >= lev1[k]); jlo |= (v1 == lev1[k]);
        }
        float prod = v0 * v1;
        atomicAdd(&lh[(i0 * 8 + j0) * 64 + col], prod);
        if (ilo)        atomicAdd(&lh[((i0 - 1) * 8 + j0) * 64 + col], prod);
        if (jlo)        atomicAdd(&lh[(i0 * 8 + (j0 - 1)) * 64 + col], prod);
        if (ilo && jlo) atomicAdd(&lh[((i0 - 1) * 8 + (j0 - 1)) * 64 + col], prod);
    }
    __syncthreads();
    if (tid < 64) {
        int bin = tid;
        float s = 0.f;
        for (int c = 0; c < 64; ++c) s += lh[bin * 64 + ((c + bin) & 63)];
        ws[OFF_PH + unit * 64 + bin] = s;
        float t = s;
        #pragma unroll
        for (int m = 1; m < 64; m <<= 1) t += __shfl_xor(t, m);
        if (bin == 0) ws[OFF_PT + unit] = t;
    }
}

struct FuseSmem {
    float hist[256]; float red[256]; float wf[144]; float we[168];
    float be[56]; float wc[64]; float bc[16]; float stat[8];
    float sw[4][8]; float tot;
};

__device__ __forceinline__ void phase_fuse(const float* __restrict__ we,
                                           const float* __restrict__ be,
                                           const float* __restrict__ wc,
                                           const float* __restrict__ bc,
                                           const float* __restrict__ wf,
                                           float* ws, int unit, int tid, FuseSmem& f)
{
    int b = unit / 7, slice = unit % 7;
    {
        int g = tid >> 6, bin = tid & 63;
        float s = 0.f;
        #pragma unroll
        for (int c = 0; c < NCHH; ++c)
            s += ws[OFF_PH + ((b * 4 + g) * NCHH + c) * 64 + bin];
        f.hist[tid] = s;
    }
    f.red[tid] = ws[OFF_PT + tid] + ws[OFF_PT + 256 + tid]
               + ws[OFF_PT + 512 + tid] + ws[OFF_PT + 768 + tid];
    if (tid < 144) f.wf[tid] = wf[tid];
    if (tid < 168) f.we[tid] = we[tid];
    if (tid < 56)  f.be[tid] = be[tid];
    if (tid < 64)  f.wc[tid] = wc[tid];
    if (tid < 16)  f.bc[tid] = bc[tid];
    __syncthreads();
    for (int k = 128; k > 0; k >>= 1) {
        if (tid < k) f.red[tid] += f.red[tid + k];
        __syncthreads();
    }
    if (tid == 0) f.tot = f.red[0];
    __syncthreads();
    float total = f.tot;

    float ls[4] = {0.f, 0.f, 0.f, 0.f}, lss[4] = {0.f, 0.f, 0.f, 0.f};
    for (int it = 0; it < 14; ++it) {
        int rem = it * 256 + tid;          // q*56+o
        int q = rem / 56, o = rem % 56;
        float basev = f.we[o * 3 + 0] * (float)(q >> 3)
                    + f.we[o * 3 + 1] * (float)(q & 7) + f.be[o];
        float w2 = f.we[o * 3 + 2];
        int cnt = ((32 * (o + 1) + 6) / 7) - ((32 * o + 6) / 7);
        float wgt = (float)(4 * cnt);
        #pragma unroll
        for (int g = 0; g < 4; ++g) {
            float y = leakyf(basev + w2 * (f.hist[g * 64 + q] / total));
            ls[g]  += y * wgt;
            lss[g] += y * y * wgt;
        }
    }
    #pragma unroll
    for (int g = 0; g < 4; ++g) {
        #pragma unroll
        for (int m = 1; m < 64; m <<= 1) {
            ls[g]  += __shfl_xor(ls[g], m);
            lss[g] += __shfl_xor(lss[g], m);
        }
    }
    int wid = tid >> 6, lane = tid & 63;
    if (lane == 0) {
        #pragma unroll
        for (int g = 0; g < 4; ++g) { f.sw[wid][g] = ls[g]; f.sw[wid][4 + g] = lss[g]; }
    }
    __syncthreads();
    if (tid < 4) {
        float m  = (f.sw[0][tid] + f.sw[1][tid] + f.sw[2][tid] + f.sw[3][tid]) / 65536.f;
        float sq = (f.sw[0][4 + tid] + f.sw[1][4 + tid]
                  + f.sw[2][4 + tid] + f.sw[3][4 + tid]) / 65536.f;
        f.stat[tid] = m;
        f.stat[4 + tid] = 1.f / sqrtf(sq - m * m + 1e-5f);
    }
    __syncthreads();

    for (int it = slice * 2; it < slice * 2 + 2; ++it) {
        int rem = it * 256 + tid;          // q*56+o
        int q = rem / 56, o = rem % 56;
        float basev = f.we[o * 3 + 0] * (float)(q >> 3)
                    + f.we[o * 3 + 1] * (float)(q & 7) + f.be[o];
        float w2 = f.we[o * 3 + 2];
        float yn[4];
        #pragma unroll
        for (int g = 0; g < 4; ++g) {
            float y = leakyf(basev + w2 * (f.hist[g * 64 + q] / total));
            yn[g] = (y - f.stat[g]) * f.stat[4 + g];
        }
        float d[9] = {0.f, 0.f, 0.f, 0.f, 0.f, 0.f, 0.f, 0.f, 0.f};
        #pragma unroll
        for (int c = 0; c < 16; ++c) {
            float z = f.bc[c];
            #pragma unroll
            for (int g = 0; g < 4; ++g) z += f.wc[c * 4 + g] * yn[g];
            z = leakyf(z);
            #pragma unroll
            for (int t = 0; t < 9; ++t) d[t] += z * f.wf[c * 9 + t];
        }
        #pragma unroll
        for (int t = 0; t < 9; ++t)
            ws[OFF_D + (b * 9 + t) * 3584 + rem] = d[t];
    }
}

__device__ __forceinline__ void phase_final(const float* __restrict__ ws,
                                            float bias, float* __restrict__ out,
                                            int t4)
{
    int b = t4 >> 14;
    int rem = t4 & 16383;
    int h = rem >> 6, w0 = (rem & 63) * 4;
    const float* Db = ws + OFF_D + b * 9 * 3584;
    float acc[4] = {bias, bias, bias, bias};
    #pragma unroll
    for (int kh = 0; kh < 3; ++kh) {
        int h2 = h + kh - 1;
        if ((unsigned)h2 > 255u) continue;
        int qr = h2 >> 2;
        #pragma unroll
        for (int kw = 0; kw < 3; ++kw) {
            const float* Dt = Db + (kh * 3 + kw) * 3584 + qr * 56;
            #pragma unroll
            for (int j = 0; j < 4; ++j) {
                int w2 = w0 + j + kw - 1;
                if ((unsigned)w2 <= 255u) acc[j] += Dt[(w2 * 7) >> 5];
            }
        }
    }
    float4 o4;
    o4.x = leakyf(acc[0]); o4.y = leakyf(acc[1]);
    o4.z = leakyf(acc[2]); o4.w = leakyf(acc[3]);
    ((float4*)out)[t4] = o4;
}

// ===================== mega (cooperative) ====================================

union Smem {
    struct { float inp[36][37]; float S[34][36]; float smn[4][8]; float smx[4][8]; } box;
    struct { float lh[64 * 64]; float sred[4]; } hist;
    FuseSmem fuse;
};

// __launch_bounds__(256, 4): 4 blocks/CU -> VGPR <= 128, guarantees 1024-block
// cooperative co-residency (LDS 16.4KB*4 = 66KB < 160KB; 16 waves/CU <= 32).
__global__ void __launch_bounds__(256, 4) k_mega(const float* __restrict__ x,
                                                 const float* __restrict__ we,
                                                 const float* __restrict__ be,
                                                 const float* __restrict__ wc,
                                                 const float* __restrict__ bc,
                                                 const float* __restrict__ wf,
                                                 const float* __restrict__ bf,
                                                 const float* __restrict__ clo,
                                                 const float* __restrict__ chi,
                                                 float* __restrict__ out,
                                                 float* __restrict__ ws)
{
    __shared__ Smem sm;
    cg::grid_group grid = cg::this_grid();
    int tid = threadIdx.x;
    int bid = blockIdx.x;               // 1024 blocks
    float lo = clo[0], hi = chi[0];

    phase_box(x, ws, lo, hi, bid >> 6, bid & 63, tid, sm.box.inp, sm.box.S,
              sm.box.smn, sm.box.smx);
    __threadfence();
    grid.sync();

    phase_hist(ws, lo, hi, bid, tid, sm.hist.lh, sm.hist.sred);
    __threadfence();
    grid.sync();

    if (bid < NB * 7) phase_fuse(we, be, wc, bc, wf, ws, bid, tid, sm.fuse);
    __threadfence();
    grid.sync();

    phase_final(ws, bf[0], out, bid * 256 + tid);
}

// ===================== fallback (4 separate kernels) =========================

__global__ void __launch_bounds__(256) k_boxmm(const float* __restrict__ x,
                                               const float* __restrict__ clo,
                                               const float* __restrict__ chi,
                                               float* __restrict__ ws)
{
    __shared__ float inp[36][37];
    __shared__ float S[34][36];
    __shared__ float smn[4][8], smx[4][8];
    phase_box(x, ws, clo[0], chi[0], blockIdx.x >> 6, blockIdx.x & 63,
              threadIdx.x, inp, S, smn, smx);
}

__global__ void __launch_bounds__(256) k_hist_part(const float* __restrict__ clo,
                                                   const float* __restrict__ chi,
                                                   float* ws)
{
    __shared__ float lh[64 * 64];
    __shared__ float sred[4];
    phase_hist(ws, clo[0], chi[0], blockIdx.x, threadIdx.x, lh, sred);
}

__global__ void __launch_bounds__(256) k_fuse(const float* __restrict__ we,
                                              const float* __restrict__ be,
                                              const float* __restrict__ wc,
                                              const float* __restrict__ bc,
                                              const float* __restrict__ wf,
                                              float* ws)
{
    __shared__ FuseSmem f;
    phase_fuse(we, be, wc, bc, wf, ws, blockIdx.x, threadIdx.x, f);
}

__global__ void __launch_bounds__(256) k_final(const float* __restrict__ ws,
                                               const float* __restrict__ bf,
                                               float* __restrict__ out)
{
    phase_final(ws, bf[0], out, blockIdx.x * 256 + threadIdx.x);
}

extern "C" void kernel_launch(void* const* d_in, const int* in_sizes, int n_in,
                              void* d_out, int out_size, void* d_ws, size_t ws_size,
                              hipStream_t stream)
{
    const float* x   = (const float*)d_in[0];
    const float* we  = (const float*)d_in[1];
    const float* be  = (const float*)d_in[2];
    const float* wc  = (const float*)d_in[3];
    const float* bc  = (const float*)d_in[4];
    const float* wf  = (const float*)d_in[5];
    const float* bfi = (const float*)d_in[6];
    const float* clo = (const float*)d_in[7];
    const float* chi = (const float*)d_in[8];
    float* out = (float*)d_out;
    float* ws  = (float*)d_ws;

    void* args[] = { (void*)&x, (void*)&we, (void*)&be, (void*)&wc, (void*)&bc,
                     (void*)&wf, (void*)&bfi, (void*)&clo, (void*)&chi,
                     (void*)&out, (void*)&ws };
    hipError_t err = hipLaunchCooperativeKernel((const void*)k_mega, dim3(1024),
                                                dim3(256), args, 0, stream);
    if (err != hipSuccess) {
        // fallback: proven 4-kernel chain (same phase bodies, same ws layout)
        k_boxmm<<<1024, 256, 0, stream>>>(x, clo, chi, ws);
        k_hist_part<<<1024, 256, 0, stream>>>(clo, chi, ws);
        k_fuse<<<NB * 7, 256, 0, stream>>>(we, be, wc, bc, wf, ws);
        k_final<<<1024, 256, 0, stream>>>(ws, bfi, out);
    }
}

// Round 9
// 132.956 us; speedup vs baseline: 5.0993x; 5.0993x over previous
//
#include <hip/hip_runtime.h>
#include <math.h>

// Problem constants
#define NB   16
#define HW   65536          // 256*256
#define NCHH 16             // hist pixel-chunks per (b,pair)

// Workspace layout (float offsets)
#define OFF_S    0          // [16][65536] channel-summed box/9
#define OFF_PH   1048576    // [1024][64] partial hists
#define OFF_PMN  1114112    // [128][64] partial mins (per 32x32 tile)
#define OFF_PMX  1122304    // [128][64] partial maxs
#define OFF_PT   1130496    // [1024] per-hist-block totals
// total floats: 1131520 (~4.53 MB)

__device__ __forceinline__ float leakyf(float v) { return v >= 0.f ? v : 0.01f * v; }

// K1: fused 3x3 box filter (zero-padded, /9) + per-tile min/max partials for all
//     8 LBP directions. One block per 32x32 tile.
__global__ void __launch_bounds__(256) k_boxmm(const float* __restrict__ x,
                                               const float* __restrict__ clo,
                                               const float* __restrict__ chi,
                                               float* __restrict__ ws)
{
    __shared__ float inp[36][37];
    __shared__ float S[34][36];
    __shared__ float smn[4][8], smx[4][8];
    const int doy[8] = {-1, 1, -1, 1, -1, 1, 0, 0};
    const int dox[8] = {-1, 1,  0, 0,  1, -1, 1, -1};
    int b = blockIdx.x >> 6, tile = blockIdx.x & 63;
    int h0 = (tile >> 3) * 32, w0 = (tile & 7) * 32;
    int tid = threadIdx.x;
    float lo = clo[0], hi = chi[0];
    const float* xb = x + (size_t)b * 3 * HW;
    for (int i = tid; i < 36 * 36; i += 256) {
        int lh = i / 36, lw = i % 36;
        int gh = h0 - 2 + lh, gw = w0 - 2 + lw;
        float v = 0.f;
        if ((unsigned)gh < 256u && (unsigned)gw < 256u) {
            int p = gh * 256 + gw;
            v = xb[p] + xb[HW + p] + xb[2 * HW + p];
        }
        inp[lh][lw] = v;
    }
    __syncthreads();
    for (int i = tid; i < 34 * 34; i += 256) {
        int lh = i / 34, lw = i % 34;
        float s = 0.f;
        #pragma unroll
        for (int dy = 0; dy < 3; ++dy)
            #pragma unroll
            for (int dx = 0; dx < 3; ++dx)
                s += inp[lh + dy][lw + dx];
        S[lh][lw] = s / 9.0f;
    }
    __syncthreads();
    #pragma unroll
    for (int i = 0; i < 4; ++i) {
        int idx = i * 256 + tid;
        int r = idx >> 5, c = idx & 31;
        ws[OFF_S + b * HW + (h0 + r) * 256 + (w0 + c)] = S[r + 1][c + 1];
    }
    float vmn[8], vmx[8];
    #pragma unroll
    for (int o = 0; o < 8; ++o) { vmn[o] = 3.4e38f; vmx[o] = -3.4e38f; }
    #pragma unroll
    for (int i = 0; i < 4; ++i) {
        int idx = i * 256 + tid;
        int r = idx >> 5, c = idx & 31;
        int gh = h0 + r, gw = w0 + c;
        float sc = S[r + 1][c + 1];
        #pragma unroll
        for (int o = 0; o < 8; ++o) {
            int nh = gh + doy[o], nw = gw + dox[o];
            float off = ((unsigned)nh < 256u && (unsigned)nw < 256u)
                        ? S[r + 1 + doy[o]][c + 1 + dox[o]] : 0.f;
            float v = fminf(fmaxf(sc - off, lo), hi);
            vmn[o] = fminf(vmn[o], v);
            vmx[o] = fmaxf(vmx[o], v);
        }
    }
    #pragma unroll
    for (int o = 0; o < 8; ++o) {
        #pragma unroll
        for (int m = 1; m < 64; m <<= 1) {
            vmn[o] = fminf(vmn[o], __shfl_xor(vmn[o], m));
            vmx[o] = fmaxf(vmx[o], __shfl_xor(vmx[o], m));
        }
    }
    int wid = tid >> 6, lane = tid & 63;
    if (lane == 0) {
        #pragma unroll
        for (int o = 0; o < 8; ++o) { smn[wid][o] = vmn[o]; smx[wid][o] = vmx[o]; }
    }
    __syncthreads();
    if (tid < 8) {
        int o = tid;
        float mn = fminf(fminf(smn[0][o], smn[1][o]), fminf(smn[2][o], smn[3][o]));
        float mx = fmaxf(fmaxf(smx[0][o], smx[1][o]), fmaxf(smx[2][o], smx[3][o]));
        ws[OFF_PMN + (b * 8 + o) * 64 + tile] = mn;
        ws[OFF_PMX + (b * 8 + o) * 64 + tile] = mx;
    }
}

// K2: partial joint 8x8 histogram per (b, pair g, chunk). Parallel min/max
//     reduce inline; writes per-block totals PT.
__global__ void __launch_bounds__(256) k_hist_part(const float* __restrict__ clo,
                                                   const float* __restrict__ chi,
                                                   float* ws)
{
    __shared__ float lh[64 * 64];   // [bin][col]
    __shared__ float sred[4];
    const int doy[8] = {-1, 1, -1, 1, -1, 1, 0, 0};
    const int dox[8] = {-1, 1,  0, 0,  1, -1, 1, -1};
    int bg = blockIdx.x >> 4, ch = blockIdx.x & 15;
    int b = bg >> 2, g = bg & 3;
    int dy0 = doy[2 * g], dx0 = dox[2 * g];
    int dy1 = doy[2 * g + 1], dx1 = dox[2 * g + 1];
    int tid = threadIdx.x;
    int warp = tid >> 6, lane = tid & 63;
    {
        int c0 = (b * 8 + 2 * g) * 64, c1 = (b * 8 + 2 * g + 1) * 64;
        float v;
        if      (warp == 0) v = ws[OFF_PMN + c0 + lane];
        else if (warp == 1) v = ws[OFF_PMX + c0 + lane];
        else if (warp == 2) v = ws[OFF_PMN + c1 + lane];
        else                v = ws[OFF_PMX + c1 + lane];
        bool isMin = (warp & 1) == 0;
        #pragma unroll
        for (int m = 1; m < 64; m <<= 1) {
            float o = __shfl_xor(v, m);
            v = isMin ? fminf(v, o) : fmaxf(v, o);
        }
        if (lane == 0) sred[warp] = v;
    }
    {
        float4 z4 = {0.f, 0.f, 0.f, 0.f};
        float4* l4 = (float4*)lh;
        l4[tid] = z4; l4[tid + 256] = z4; l4[tid + 512] = z4; l4[tid + 768] = z4;
    }
    __syncthreads();
    float mn0 = sred[0], mx0 = sred[1], mn1 = sred[2], mx1 = sred[3];
    float r0 = mx0 - mn0, r1 = mx1 - mn1;
    float lev0[8], lev1[8];
    #pragma unroll
    for (int q = 0; q < 8; ++q) {
        lev0[q] = __fadd_rn(mn0, __fmul_rn(r0, (float)q * 0.125f));
        lev1[q] = __fadd_rn(mn1, __fmul_rn(r1, (float)q * 0.125f));
    }
    const float* Sb = ws + OFF_S + b * HW;
    int col = tid & 63;
    float lo = clo[0], hi = chi[0];
    int base = ch * (HW / NCHH);
    #pragma unroll
    for (int it = 0; it < (HW / NCHH) / 256; ++it) {
        int p = base + it * 256 + tid;
        int h = p >> 8, w = p & 255;
        float off0 = 0.f, off1 = 0.f;
        int nh = h + dy0, nw = w + dx0;
        if ((unsigned)nh < 256u && (unsigned)nw < 256u) off0 = Sb[nh * 256 + nw];
        nh = h + dy1; nw = w + dx1;
        if ((unsigned)nh < 256u && (unsigned)nw < 256u) off1 = Sb[nh * 256 + nw];
        float sc = Sb[p];
        float v0 = fminf(fmaxf(sc - off0, lo), hi);
        float v1 = fminf(fmaxf(sc - off1, lo), hi);
        int i0 = 0, j0 = 0;
        bool ilo = false, jlo = false;
        #pragma unroll
        for (int k = 1; k < 8; ++k) {
            i0 += (v0 >= lev0[k]); ilo |= (v0 == lev0[k]);
            j0 += (v1 >= lev1[k]); jlo |= (v1 == lev1[k]);
        }
        float prod = v0 * v1;
        atomicAdd(&lh[(i0 * 8 + j0) * 64 + col], prod);
        if (ilo)        atomicAdd(&lh[((i0 - 1) * 8 + j0) * 64 + col], prod);
        if (jlo)        atomicAdd(&lh[(i0 * 8 + (j0 - 1)) * 64 + col], prod);
        if (ilo && jlo) atomicAdd(&lh[((i0 - 1) * 8 + (j0 - 1)) * 64 + col], prod);
    }
    __syncthreads();
    if (tid < 64) {
        int bin = tid;
        float s = 0.f;
        for (int c = 0; c < 64; ++c) s += lh[bin * 64 + ((c + bin) & 63)];
        ws[OFF_PH + blockIdx.x * 64 + bin] = s;
        float t = s;
        #pragma unroll
        for (int m = 1; m < 64; m <<= 1) t += __shfl_xor(t, m);
        if (bin == 0) ws[OFF_PT + blockIdx.x] = t;
    }
}

// K3: fused stats + channel-mix + final conv. 1024 blocks; block bid covers
//     image rows h_base..h_base+3 of batch b (b=bid>>6, h_base=(bid&63)*4).
//     Needs D[t][qr][o] only for qr in {k-1,k,k+1}, k=bid&63 -> 6KB LDS.
__global__ void __launch_bounds__(256) k_fuse_final(const float* __restrict__ we,
                                                    const float* __restrict__ be,
                                                    const float* __restrict__ wc,
                                                    const float* __restrict__ bc,
                                                    const float* __restrict__ wf,
                                                    const float* __restrict__ bf,
                                                    const float* __restrict__ ws,
                                                    float* __restrict__ out)
{
    __shared__ float sh_hist[256];      // [g][bin]
    __shared__ float sh_red[256];
    __shared__ float sh_wf[144];
    __shared__ float sh_we[168];
    __shared__ float sh_be[56];
    __shared__ float sh_wc[64];
    __shared__ float sh_bc[16];
    __shared__ float sh_stat[8];        // mean[4], istd[4]
    __shared__ float sw[4][8];
    __shared__ float sh_tot;
    __shared__ float Dl[9][3][56];      // D[t][qr-qr_base][o]
    int bid = blockIdx.x;
    int tid = threadIdx.x;
    int b = bid >> 6, k = bid & 63;
    int qr_base = k - 1;

    // phase A: per-(g,bin) hist sums for this batch
    {
        int g = tid >> 6, bin = tid & 63;
        float s = 0.f;
        #pragma unroll
        for (int c = 0; c < NCHH; ++c)
            s += ws[OFF_PH + ((b * 4 + g) * NCHH + c) * 64 + bin];
        sh_hist[tid] = s;
    }
    // phase B: global total via per-block totals
    sh_red[tid] = ws[OFF_PT + tid] + ws[OFF_PT + 256 + tid]
                + ws[OFF_PT + 512 + tid] + ws[OFF_PT + 768 + tid];
    if (tid < 144) sh_wf[tid] = wf[tid];
    if (tid < 168) sh_we[tid] = we[tid];
    if (tid < 56)  sh_be[tid] = be[tid];
    if (tid < 64)  sh_wc[tid] = wc[tid];
    if (tid < 16)  sh_bc[tid] = bc[tid];
    __syncthreads();
    for (int s = 128; s > 0; s >>= 1) {
        if (tid < s) sh_red[tid] += sh_red[tid + s];
        __syncthreads();
    }
    if (tid == 0) sh_tot = sh_red[0];
    __syncthreads();
    float total = sh_tot;

    // phase C: weighted instance-norm stats (row repeat = 4; col repeat cnt(o))
    float ls[4] = {0.f, 0.f, 0.f, 0.f}, lss[4] = {0.f, 0.f, 0.f, 0.f};
    for (int it = 0; it < 14; ++it) {
        int rem = it * 256 + tid;          // q*56+o
        int q = rem / 56, o = rem % 56;
        float basev = sh_we[o * 3 + 0] * (float)(q >> 3)
                    + sh_we[o * 3 + 1] * (float)(q & 7) + sh_be[o];
        float w2 = sh_we[o * 3 + 2];
        int cnt = ((32 * (o + 1) + 6) / 7) - ((32 * o + 6) / 7);
        float wgt = (float)(4 * cnt);
        #pragma unroll
        for (int g = 0; g < 4; ++g) {
            float y = leakyf(basev + w2 * (sh_hist[g * 64 + q] / total));
            ls[g]  += y * wgt;
            lss[g] += y * y * wgt;
        }
    }
    #pragma unroll
    for (int g = 0; g < 4; ++g) {
        #pragma unroll
        for (int m = 1; m < 64; m <<= 1) {
            ls[g]  += __shfl_xor(ls[g], m);
            lss[g] += __shfl_xor(lss[g], m);
        }
    }
    int wid = tid >> 6, lane = tid & 63;
    if (lane == 0) {
        #pragma unroll
        for (int g = 0; g < 4; ++g) { sw[wid][g] = ls[g]; sw[wid][4 + g] = lss[g]; }
    }
    __syncthreads();
    if (tid < 4) {
        float m  = (sw[0][tid] + sw[1][tid] + sw[2][tid] + sw[3][tid]) / 65536.f;
        float sq = (sw[0][4 + tid] + sw[1][4 + tid]
                  + sw[2][4 + tid] + sw[3][4 + tid]) / 65536.f;
        sh_stat[tid] = m;
        sh_stat[4 + tid] = 1.f / sqrtf(sq - m * m + 1e-5f);
    }
    __syncthreads();

    // phase D: materialize needed D cells (3 qr x 56 o = 168 cells) in LDS
    if (tid < 168) {
        int i = tid / 56, o = tid % 56;
        int q = qr_base + i;
        if ((unsigned)q < 64u) {
            float basev = sh_we[o * 3 + 0] * (float)(q >> 3)
                        + sh_we[o * 3 + 1] * (float)(q & 7) + sh_be[o];
            float w2 = sh_we[o * 3 + 2];
            float yn[4];
            #pragma unroll
            for (int g = 0; g < 4; ++g) {
                float y = leakyf(basev + w2 * (sh_hist[g * 64 + q] / total));
                yn[g] = (y - sh_stat[g]) * sh_stat[4 + g];
            }
            float d[9] = {0.f, 0.f, 0.f, 0.f, 0.f, 0.f, 0.f, 0.f, 0.f};
            #pragma unroll
            for (int c = 0; c < 16; ++c) {
                float z = sh_bc[c];
                #pragma unroll
                for (int g = 0; g < 4; ++g) z += sh_wc[c * 4 + g] * yn[g];
                z = leakyf(z);
                #pragma unroll
                for (int t = 0; t < 9; ++t) d[t] += z * sh_wf[c * 9 + t];
            }
            #pragma unroll
            for (int t = 0; t < 9; ++t) Dl[t][i][o] = d[t];
        }
    }
    __syncthreads();

    // phase E: gather 4 pixels/thread, float4 store
    {
        int t4 = bid * 256 + tid;              // quad index
        int rem = t4 & 16383;
        int h = rem >> 6, w0 = (rem & 63) * 4;
        float bias = bf[0];
        float acc[4] = {bias, bias, bias, bias};
        #pragma unroll
        for (int kh = 0; kh < 3; ++kh) {
            int h2 = h + kh - 1;
            if ((unsigned)h2 > 255u) continue;
            int i = (h2 >> 2) - qr_base;
            #pragma unroll
            for (int kw = 0; kw < 3; ++kw) {
                const float* Dt = &Dl[kh * 3 + kw][i][0];
                #pragma unroll
                for (int j = 0; j < 4; ++j) {
                    int w2 = w0 + j + kw - 1;
                    if ((unsigned)w2 <= 255u) acc[j] += Dt[(w2 * 7) >> 5];
                }
            }
        }
        float4 o4;
        o4.x = leakyf(acc[0]); o4.y = leakyf(acc[1]);
        o4.z = leakyf(acc[2]); o4.w = leakyf(acc[3]);
        ((float4*)out)[t4] = o4;
    }
}

extern "C" void kernel_launch(void* const* d_in, const int* in_sizes, int n_in,
                              void* d_out, int out_size, void* d_ws, size_t ws_size,
                              hipStream_t stream)
{
    const float* x   = (const float*)d_in[0];
    const float* we  = (const float*)d_in[1];
    const float* be  = (const float*)d_in[2];
    const float* wc  = (const float*)d_in[3];
    const float* bc  = (const float*)d_in[4];
    const float* wf  = (const float*)d_in[5];
    const float* bfi = (const float*)d_in[6];
    const float* clo = (const float*)d_in[7];
    const float* chi = (const float*)d_in[8];
    float* out = (float*)d_out;
    float* ws  = (float*)d_ws;

    k_boxmm<<<1024, 256, 0, stream>>>(x, clo, chi, ws);
    k_hist_part<<<1024, 256, 0, stream>>>(clo, chi, ws);
    k_fuse_final<<<1024, 256, 0, stream>>>(we, be, wc, bc, wf, bfi, ws, out);
}